// Round 7
// baseline (50.049 us; speedup 1.0000x reference)
//
#include <hip/hip_runtime.h>
#include <hip/hip_bf16.h>

// ws layout (requires ws_size >= 17039360 B):
//   [0, 221184)        : weights as bf16 in 32x32x16 MFMA B-fragment order
//   [221184, 221440)   : 256 B of zeros (OOB halo source)
//   [262144, 17039360) : x_t = x transposed to [b][s][c] bf16 (16 MiB)
#define WS_W_OFF    0
#define WS_ZERO_OFF 221184
#define WS_XT_OFF   262144

typedef __attribute__((ext_vector_type(8)))  short s16x8;
typedef __attribute__((ext_vector_type(4)))  float f32x4;
typedef __attribute__((ext_vector_type(16))) float f32x16;

#define GLOBAL_AS __attribute__((address_space(1)))
#define LDS_AS    __attribute__((address_space(3)))

__device__ __forceinline__ unsigned short f2bf(float f) {
  unsigned u = __builtin_bit_cast(unsigned, f);
  u = u + 0x7fffu + ((u >> 16) & 1u);
  return (unsigned short)(u >> 16);
}

// ---------------------------------------------------------------------------
// Fused prep: blocks [0,432) repack weights; blocks [432,4528) transpose x.
//
// Weights -> 32x32x16 B-fragments. Fragment f = nt*2+ks of (tap,h) holds
// B[n][k]: n = cout = nt*32 + (l&31), k(cin) = h*32 + ks*16 + (l>>5)*8 + j.
// bf16 index = (((tap*2+h)*4 + f)*64 + l)*8 + j  (4 KB per (tap,h) tile).
//
// x: NCDHW fp32 -> x_t[b][s][c] bf16 (channels-last). Reads coalesced along s.
__global__ void prep_kernel(const float* __restrict__ x,
                            const float* __restrict__ w,
                            unsigned short* __restrict__ wsw,
                            float* __restrict__ zeros,
                            unsigned short* __restrict__ xt) {
  int blk = blockIdx.x;
  if (blk < 432) {
    int t = blk * 256 + threadIdx.x;             // 110592 threads exactly
    int tap  = t % 27;
    int cin  = (t / 27) & 63;
    int cout = t / (27 * 64);
    int h  = cin >> 5;
    int c5 = cin & 31;
    int ks = c5 >> 4;
    int hi = (c5 >> 3) & 1;
    int j  = c5 & 7;
    int nt = cout >> 5;
    int l  = hi * 32 + (cout & 31);
    int f  = nt * 2 + ks;
    int dst = (((tap * 2 + h) * 4 + f) * 64 + l) * 8 + j;
    wsw[dst] = f2bf(w[t]);
    if (t < 64) zeros[t] = 0.0f;
  } else {
    int t  = (blk - 432) * 256 + threadIdx.x;    // 1048576 threads
    int s  = t & 32767;
    int c8 = (t >> 15) & 7;
    int b  = t >> 18;
    const float* src = x + (size_t)(b * 64 + c8 * 8) * 32768 + s;
    s16x8 v;
    #pragma unroll
    for (int k = 0; k < 8; ++k) v[k] = (short)f2bf(src[(size_t)k * 32768]);
    *(s16x8*)(xt + (size_t)(b * 32768 + s) * 64 + c8 * 8) = v;
  }
}

// ---------------------------------------------------------------------------
// Implicit-GEMM conv, 32x32x16 MFMA, fully unrolled 27-tap K-loop.
// Block = (b, z-pair, y-quad): 2z x 4y x 32x = 256 outputs x 64 couts,
// 4 waves. Wave w: z = z0+(w>>1), y-rows {y0+2(w&1), +1}; per wave
// 2 m-tiles (y-rows) x 2 n-tiles (cout 32s), acc[2][2] f32x16.
// K = 64 as two cin-halves; halo per half: 4z x 6y x 34x pos x 64 B = 52 KB.
// 27 taps fully unrolled (compile-time kd/kh/kw: no div/mod, SGPR+imm B
// addresses), A/B triple-buffered at depth 2, ZERO barriers inside the loop.
//
// Halo: position p at halo[p*64]; 16B chunk c stored at slot c ^ ((p>>1)&3).
// A-read (lane l: p += l&31, c = ks*2 + (l>>5)) lands exactly 8 of the wave's
// 256 dwords on each bank -> b128 floor, conflict-free. Staging dest stays
// linear (global_load_lds rule); the swizzle is applied to the SOURCE chunk,
// which is the per-lane constant (l&3) ^ ((l>>3)&3).
__global__ __launch_bounds__(256, 2) void conv_kernel(const float* __restrict__ bias,
                                                      float* __restrict__ out,
                                                      const char* __restrict__ ws) {
  __shared__ __align__(16) unsigned char halo[52 * 1024];  // 832 pos (816 used)

  const int tid  = threadIdx.x;
  const int lane = tid & 63;
  const int w    = tid >> 6;                     // wave id 0..3
  // XCD-aware swizzle (512 % 8 == 0 -> bijective): each XCD gets 64 contiguous
  // logical blocks (fixed b, 8 consecutive z-pairs) -> ~2.4 MB x_t slab in L2.
  const int logical = (blockIdx.x & 7) * 64 + (blockIdx.x >> 3);
  const int yt = logical & 7, zt = (logical >> 3) & 15, b = logical >> 7;
  const int z0 = zt * 2, y0 = yt * 4;
  const int zo  = w >> 1;
  const int yo2 = (w & 1) * 2;

  const int q31 = lane & 31;
  const int hi  = lane >> 5;

  // staging: granule = 1024 B = 16 positions; lane l -> pos g*16 + (l>>2),
  // dest slot l&3, source chunk (l&3) ^ ((l>>3)&3)  (matches read swizzle).
  const int sl_sub   = lane >> 2;
  const int sl_chunk = (lane & 3) ^ ((lane >> 3) & 3);

  auto stage_halo = [&](int h) {
    for (int g = w; g < 52; g += 4) {            // 13 granules per wave
      int pos = g * 16 + sl_sub;
      int hz = pos / 204; int rem = pos - hz * 204;        // 204 = 6*34
      int hy = rem / 34;  int hx = rem - hy * 34;
      int gz = z0 + hz - 1, gy = y0 + hy - 1, gx = hx - 1;
      bool inb = (pos < 816) & ((unsigned)gz < 32u) &
                 ((unsigned)gy < 32u) & ((unsigned)gx < 32u);
      int s = (gz * 32 + gy) * 32 + gx;
      int src = inb ? (WS_XT_OFF + (b * 32768 + s) * 128 + h * 64 + sl_chunk * 16)
                    : WS_ZERO_OFF;
      __builtin_amdgcn_global_load_lds(
          (const GLOBAL_AS void*)(ws + src),
          (LDS_AS void*)(&halo[g * 1024 + lane * 16]),
          16, 0, 0);
    }
  };

  const s16x8* __restrict__ wfr = (const s16x8*)(ws + WS_W_OFF);

  f32x16 acc[2][2];
  #pragma unroll
  for (int mt = 0; mt < 2; ++mt)
    #pragma unroll
    for (int nt = 0; nt < 2; ++nt)
      #pragma unroll
      for (int r = 0; r < 16; ++r) acc[mt][nt][r] = 0.0f;

  s16x8 Ab[3][4], Bb[3][4];
  const int pA0 = (zo * 6 + yo2) * 34 + q31;     // m-tile 0 halo base
  const int pA1 = pA0 + 34;                      // m-tile 1

  auto loadB = [&](int slot, int h, int tap) {
    #pragma unroll
    for (int f = 0; f < 4; ++f)
      Bb[slot][f] = wfr[((tap * 2 + h) * 4 + f) * 64 + lane];
  };

  auto loadA = [&](int slot, int tap) {
    const int kd = tap / 9, r9 = tap - kd * 9;
    const int kh = r9 / 3, kw = r9 - kh * 3;     // compile-time after unroll
    const int d  = (kd * 6 + kh) * 34 + kw;
    #pragma unroll
    for (int mt = 0; mt < 2; ++mt) {
      int p = (mt ? pA1 : pA0) + d;
      #pragma unroll
      for (int ks = 0; ks < 2; ++ks) {
        int swz = ((ks << 1) | hi) ^ ((p >> 1) & 3);
        Ab[slot][mt * 2 + ks] = *(const s16x8*)&halo[(p << 6) + (swz << 4)];
      }
    }
  };

  auto compute = [&](int slot) {
    #pragma unroll
    for (int ks = 0; ks < 2; ++ks)
      #pragma unroll
      for (int mt = 0; mt < 2; ++mt)
        #pragma unroll
        for (int nt = 0; nt < 2; ++nt)
          acc[mt][nt] = __builtin_amdgcn_mfma_f32_32x32x16_bf16(
              Ab[slot][mt * 2 + ks], Bb[slot][nt * 2 + ks], acc[mt][nt], 0, 0, 0);
  };

  // 27 taps, fully unrolled, depth-2 prefetch, no barriers inside.
  auto run27 = [&](int h) {
    loadA(0, 0); loadA(1, 1);
    #pragma unroll
    for (int tap = 0; tap < 27; ++tap) {
      if (tap < 25) {
        loadB((tap + 2) % 3, h, tap + 2);
        loadA((tap + 2) % 3, tap + 2);
      }
      compute(tap % 3);
    }
  };

  stage_halo(0);
  loadB(0, 0, 0); loadB(1, 0, 1);    // B prologue overlaps halo staging
  __syncthreads();                   // drains vmcnt; halo 0 ready
  run27(0);

  loadB(0, 1, 0); loadB(1, 1, 1);    // half-1 B prologue (doesn't touch halo)
  __syncthreads();                   // all waves done reading half-0 halo
  stage_halo(1);
  __syncthreads();                   // halo 1 ready
  run27(1);

  // ---- epilogue: 32x32 C/D layout (m74/m101): col(cout) = lane&31,
  // row(x) = (reg&3) + 8*(reg>>2) + 4*(lane>>5) ----
  const int z = z0 + zo;
  #pragma unroll
  for (int nt = 0; nt < 2; ++nt) {
    int cout = nt * 32 + q31;
    float bv = bias[cout];
    #pragma unroll
    for (int mt = 0; mt < 2; ++mt) {
      int y = y0 + yo2 + mt;
      float* orow = out + ((size_t)((b * 64 + cout) * 32 + z) * 32 + y) * 32;
      #pragma unroll
      for (int q = 0; q < 4; ++q) {
        int x0 = q * 8 + hi * 4;
        f32x4 v;
        #pragma unroll
        for (int r = 0; r < 4; ++r) v[r] = acc[mt][nt][q * 4 + r] + bv;
        *(f32x4*)&orow[x0] = v;
      }
    }
  }
}

extern "C" void kernel_launch(void* const* d_in, const int* in_sizes, int n_in,
                              void* d_out, int out_size, void* d_ws, size_t ws_size,
                              hipStream_t stream) {
  const float* x    = (const float*)d_in[0];
  const float* wgt  = (const float*)d_in[1];
  const float* bias = (const float*)d_in[2];
  float* out = (float*)d_out;
  char* ws = (char*)d_ws;

  prep_kernel<<<4528, 256, 0, stream>>>(x, wgt,
                                        (unsigned short*)(ws + WS_W_OFF),
                                        (float*)(ws + WS_ZERO_OFF),
                                        (unsigned short*)(ws + WS_XT_OFF));
  conv_kernel<<<512, 256, 0, stream>>>(bias, out, ws);
}